// Round 17
// baseline (432.672 us; speedup 1.0000x reference)
//
#include <hip/hip_runtime.h>
#include <math.h>

#define NN_ 32768      // nodes
#define NE_ 49152      // edges
#define NG_ 1024       // graphs

typedef short bh8 __attribute__((ext_vector_type(8)));   // 8 bf16 bit-patterns (4 VGPR)
typedef float f32x4 __attribute__((ext_vector_type(4)));

__device__ __forceinline__ unsigned short f2bfu(float f) {   // RNE float->bf16 bits
    union { float f; unsigned int i; } x; x.f = f;
    unsigned int u = x.i;
    u += 0x7FFFu + ((u >> 16) & 1u);
    return (unsigned short)(u >> 16);
}
__device__ __forceinline__ float sigm(float x) { return 1.f / (1.f + expf(-x)); }

// Kept for harness compatibility (unused).
__global__ void MPNN_78632261256134_kernel() {}

// ---------------- fused init zero: deg (int) | agg ----------------
__global__ void k_init(int* deg, float* agg) {
    int i = blockIdx.x * 256 + threadIdx.x;
    if (i < NN_) deg[i] = 0;
    int k = i - NN_;
    if (k >= 0 && k < NN_ * 64) agg[k] = 0.f;
}

// ---------------- lin0 ----------------
__global__ void k_lin0(const float* x, const float* W, const float* b, float* node) {
    int g = blockIdx.x * 256 + threadIdx.x;   // n*64+d
    int n = g >> 6, d = g & 63;
    const float* xr = x + n * 14;
    const float* wr = W + d * 14;
    float acc = b[d];
    for (int i = 0; i < 14; i++) acc += xr[i] * wr[i];
    node[g] = fmaxf(acc, 0.f);
}

// ---------------- in-degree count (int) ----------------
__global__ void k_cnt(const int* dst, int* deg) {
    int e = blockIdx.x * 256 + threadIdx.x;
    if (e < NE_) atomicAdd(&deg[dst[e]], 1);
}

// ---------------- two-phase parallel prefix scan ----------------
__global__ __launch_bounds__(256) void k_scanA(const int* __restrict__ deg,
                                               int* __restrict__ offs,
                                               int* __restrict__ bsum) {
    __shared__ int wtot[4];
    int tid = threadIdx.x, bid = blockIdx.x;
    int i = bid * 256 + tid;
    int v = deg[i];
    int sc = v;
    for (int o = 1; o < 64; o <<= 1) { int u = __shfl_up(sc, o); if ((tid & 63) >= o) sc += u; }
    if ((tid & 63) == 63) wtot[tid >> 6] = sc;
    __syncthreads();
    int wpre = 0;
    for (int k = 0; k < (tid >> 6); k++) wpre += wtot[k];
    offs[i] = sc + wpre - v;              // exclusive within block
    if (tid == 255) bsum[bid] = sc + wpre; // block total
}

__global__ __launch_bounds__(256) void k_scanC(const int* __restrict__ bsum,
                                               int* __restrict__ offs,
                                               int* __restrict__ head) {
    __shared__ int boff;
    int tid = threadIdx.x, bid = blockIdx.x;
    if (tid == 0) {
        int s = 0;
        for (int k = 0; k < bid; k++) s += bsum[k];
        boff = s;
    }
    __syncthreads();
    int i = bid * 256 + tid;
    int o = offs[i] + boff;
    offs[i] = o; head[i] = o;
    if (i == NN_ - 1) offs[NN_] = NE_;
}

// ---------------- scatter: perm = edges sorted by dst (counting sort) ----------------
__global__ void k_scatter(const int* __restrict__ dst, int* __restrict__ head,
                          int* __restrict__ perm) {
    int e = blockIdx.x * 256 + threadIdx.x;
    if (e < NE_) { int p = atomicAdd(&head[dst[e]], 1); perm[p] = e; }
}

// ---------------- graph segment bounds for Set2Set ----------------
__global__ void k_gbnd(const int* __restrict__ batch, int* __restrict__ gb) {
    int n = blockIdx.x * 256 + threadIdx.x;
    if (n >= NN_) return;
    int b = batch[n];
    if (n == 0) { for (int g = 0; g <= b; g++) gb[g] = 0; }
    else {
        int pb = batch[n - 1];
        for (int g = pb + 1; g <= b; g++) gb[g] = n;
    }
    if (n == NN_ - 1) { for (int g = b + 1; g <= NG_; g++) gb[g] = NN_; }
}

// ---------------- weight transposes for s2s3/fc ----------------
__global__ void k_tw(const float* lWih, const float* lWhh, float* WihT2, float* WhhT2,
                     const float* fc1W, float* fc1WT) {
    int t = blockIdx.x * 256 + threadIdx.x;
    if (t < 32768) {
        int r = t >> 7, cc = t & 127; WihT2[cc * 256 + r] = lWih[t];
    } else if (t < 49152) {
        int u = t - 32768; int r = u >> 6, cc = u & 63; WhhT2[cc * 256 + r] = lWhh[u];
    } else if (t < 65536) {
        int u = t - 49152; int r = u >> 7, cc = u & 127; fc1WT[cc * 128 + r] = fc1W[u];
    }
}

// ---------------- GRU weight B-fragments, bf16x2 hi/lo (once) ----------------
__global__ void k_wfrag(const float* __restrict__ gWih, const float* __restrict__ gWhh,
                        const float* __restrict__ rootW,
                        unsigned short* __restrict__ HHh, unsigned short* __restrict__ HHl,
                        unsigned short* __restrict__ IHh, unsigned short* __restrict__ IHl) {
    int idx = blockIdx.x * 256 + threadIdx.x;   // < 28672
    if (idx >= 28672) return;
    float w;
    unsigned short *oh, *ol;
    if (idx < 16384) {
        int f = idx;
        int tile = f >> 9, within = f & 511;
        int l = within >> 3, j = within & 7;
        int ot = tile >> 1, kt = tile & 1;
        int col = ot * 16 + (l & 15);
        int k = kt * 32 + (l >> 4) * 8 + j;
        w = (col < 192) ? gWhh[col * 64 + k] : rootW[k * 64 + (col - 192)];
        oh = HHh + f; ol = HHl + f;
    } else {
        int f = idx - 16384;
        int tile = f >> 9, within = f & 511;
        int l = within >> 3, j = within & 7;
        int ot = tile >> 1, kt = tile & 1;
        int col = ot * 16 + (l & 15);
        int k = kt * 32 + (l >> 4) * 8 + j;
        w = gWih[col * 64 + k];
        oh = IHh + f; ol = IHl + f;
    }
    unsigned short hi = f2bfu(w);
    union { unsigned int i; float f; } hv; hv.i = (unsigned int)hi << 16;
    unsigned short lo = f2bfu(w - hv.f);
    *oh = hi; *ol = lo;
}

// ---------------- Bhat3: frag-contiguous bf16 B [s][w][t][lane][8] ----------------
__global__ void k_bhat3(const float* e2W, unsigned short* Bhat3) {
    int idx = blockIdx.x * 256 + threadIdx.x;   // < 524288
    if (idx >= 64 * 4 * 4 * 64 * 8) return;
    int j = idx & 7, lane = (idx >> 3) & 63, t = (idx >> 9) & 3, w = (idx >> 11) & 3, s = idx >> 13;
    int row = s * 64 + w * 16 + (lane & 15);
    int k = t * 32 + (lane >> 4) * 8 + j;
    Bhat3[idx] = f2bfu(e2W[row * 128 + k]);
}

// ---------------- Hhat: frag-ready He in dst-sorted edge order ----------------
__global__ __launch_bounds__(256) void k_he(const float* __restrict__ ea,
                                            const float* __restrict__ e1W,
                                            const float* __restrict__ e1b,
                                            const int* __restrict__ perm,
                                            unsigned short* __restrict__ Hhat) {
    int tid = threadIdx.x;
    int lane = tid & 63, sub = tid >> 6;
    int gi = blockIdx.x * 4 + sub;            // < 12288
    int etile = gi >> 2, t = gi & 3;
    int e = etile * 16 + (lane & 15), quad = lane >> 4;
    int eo = perm[e];
    const float* ar = ea + (size_t)eo * 4;
    float a0 = ar[0], a1 = ar[1], a2 = ar[2], a3 = ar[3];
    union { unsigned short u[8]; uint4 q; } o;
#pragma unroll
    for (int j = 0; j < 8; j++) {
        int c = t * 32 + quad * 8 + j;
        const float* wr = e1W + c * 4;
        float h = e1b[c] + a0 * wr[0] + a1 * wr[1] + a2 * wr[2] + a3 * wr[3];
        o.u[j] = f2bfu(fmaxf(h, 0.f));
    }
    *(uint4*)(Hhat + (size_t)gi * 512 + lane * 8) = o.q;
}

// ---------------- MFMA NNConv: 192 edges/block, 8 waves share the B stream ----------------
// Waves: w2 = wave&1 selects output-dim pair {2*w2, 2*w2+1}; m2 = wave>>1 selects 3
// edge-tiles {m2*3..m2*3+2}. Waves with equal w2 read IDENTICAL B tiles -> L1 serves
// 3 of 4 requests; distinct B per block per s stays 16KB but covers 192 edges (3x the
// old 64) -> total L2 B traffic 768 -> 256MB. Grid = 256 = exactly 1 block/CU (no tail).
// Per-wave regs: af[3][4]=48 + Bdbl 64 + acc 24 + msg 24 + misc ~ 185 < 256.
#define PS(S) (((S) + soff) & 63)

#define LDB8(B, S) {                                                                      \
        const unsigned short* _p = Bhat3 + (size_t)PS(S) * 8192 + (w2 * 2) * 2048 + lane * 8; \
        _Pragma("unroll")                                                                 \
        for (int j_ = 0; j_ < 2; j_++)                                                    \
            _Pragma("unroll")                                                             \
            for (int t_ = 0; t_ < 4; t_++)                                                \
                (B)[j_][t_] = *(const bh8*)(const void*)(_p + j_ * 2048 + t_ * 512); }

__global__ __launch_bounds__(512) void k_convr(const float* __restrict__ node,
                                               const unsigned short* __restrict__ Hhat,
                                               const unsigned short* __restrict__ Bhat3,
                                               const float* __restrict__ e2b,
                                               const int* __restrict__ src,
                                               const int* __restrict__ dst,
                                               const int* __restrict__ perm,
                                               float* __restrict__ agg) {
    __shared__ __align__(16) float xs[64 * 204];   // xs[s][e<192]; epilogue: ms[192][68]
    __shared__ int dst_s[192];

    const int tid = threadIdx.x;
    const int eb = blockIdx.x * 192;
    const int lane = tid & 63, w8 = tid >> 6;
    const int w2 = w8 & 1, m2 = w8 >> 1;
    const int quad = lane >> 4, mrow = lane & 15;
    const int soff = (blockIdx.x * 37) & 63;

    {   // stage x[src] transposed for 192 edges: 768 (edge,16-dim) units over 512 threads
#pragma unroll
        for (int base = 0; base < 768; base += 512) {
            int u = base + tid;
            if (u < 768) {
                int r = u >> 2, c = u & 3;
                int s = src[perm[eb + r]];
                const float* nr = node + (size_t)s * 64 + c * 16;
#pragma unroll
                for (int j = 0; j < 16; j++) xs[(c * 16 + j) * 204 + r] = nr[j];
            }
        }
        if (tid < 192) dst_s[tid] = dst[perm[eb + tid]];
    }

    bh8 af[3][4];   // this wave's 3 edge-tiles x 4 k-tiles
#pragma unroll
    for (int i = 0; i < 3; i++)
#pragma unroll
        for (int t = 0; t < 4; t++)
            af[i][t] = *(const bh8*)(const void*)(
                Hhat + (size_t)(((eb >> 4) + m2 * 3 + i) * 4 + t) * 512 + lane * 8);
    __syncthreads();

    const f32x4 z4 = {0.f, 0.f, 0.f, 0.f};
    f32x4 msg[3][2];
#pragma unroll
    for (int i = 0; i < 3; i++)
#pragma unroll
        for (int j = 0; j < 2; j++) msg[i][j] = z4;

    bh8 b0[2][4], b1[2][4];
    LDB8(b0, 0)

#pragma unroll 1
    for (int s = 0; s < 64; s += 2) {
        // even s: use b0, prefetch b1
        if (s + 1 < 64) LDB8(b1, s + 1)
        {
            float bbv0 = e2b[PS(s) * 64 + (w2 * 2) * 16 + mrow];
            float bbv1 = e2b[PS(s) * 64 + (w2 * 2 + 1) * 16 + mrow];
            f32x4 acc[3][2];
            __builtin_amdgcn_s_setprio(1);
#pragma unroll
            for (int t = 0; t < 4; t++)
#pragma unroll
                for (int i = 0; i < 3; i++)
#pragma unroll
                    for (int j = 0; j < 2; j++)
                        acc[i][j] = __builtin_amdgcn_mfma_f32_16x16x32_bf16(
                            af[i][t], b0[j][t], (t == 0) ? z4 : acc[i][j], 0, 0, 0);
            __builtin_amdgcn_s_setprio(0);
            int sp = PS(s);
#pragma unroll
            for (int i = 0; i < 3; i++) {
                f32x4 xv = *(const f32x4*)(const void*)(
                    xs + sp * 204 + (m2 * 3 + i) * 16 + quad * 4);
#pragma unroll
                for (int r = 0; r < 4; r++) {
                    msg[i][0][r] += xv[r] * (acc[i][0][r] + bbv0);
                    msg[i][1][r] += xv[r] * (acc[i][1][r] + bbv1);
                }
            }
        }
        // odd s: use b1, prefetch b0
        if (s + 2 < 64) LDB8(b0, s + 2)
        if (s + 1 < 64) {
            float bbv0 = e2b[PS(s + 1) * 64 + (w2 * 2) * 16 + mrow];
            float bbv1 = e2b[PS(s + 1) * 64 + (w2 * 2 + 1) * 16 + mrow];
            f32x4 acc[3][2];
            __builtin_amdgcn_s_setprio(1);
#pragma unroll
            for (int t = 0; t < 4; t++)
#pragma unroll
                for (int i = 0; i < 3; i++)
#pragma unroll
                    for (int j = 0; j < 2; j++)
                        acc[i][j] = __builtin_amdgcn_mfma_f32_16x16x32_bf16(
                            af[i][t], b1[j][t], (t == 0) ? z4 : acc[i][j], 0, 0, 0);
            __builtin_amdgcn_s_setprio(0);
            int sp = PS(s + 1);
#pragma unroll
            for (int i = 0; i < 3; i++) {
                f32x4 xv = *(const f32x4*)(const void*)(
                    xs + sp * 204 + (m2 * 3 + i) * 16 + quad * 4);
#pragma unroll
                for (int r = 0; r < 4; r++) {
                    msg[i][0][r] += xv[r] * (acc[i][0][r] + bbv0);
                    msg[i][1][r] += xv[r] * (acc[i][1][r] + bbv1);
                }
            }
        }
    }

    // ---- epilogue: transpose msg via xs [192 edges][68], per-window segment reduce ----
    __syncthreads();   // all waves done reading xs
#pragma unroll
    for (int i = 0; i < 3; i++)
#pragma unroll
        for (int j = 0; j < 2; j++)
#pragma unroll
            for (int r = 0; r < 4; r++)
                xs[((m2 * 3 + i) * 16 + quad * 4 + r) * 68 + (w2 * 2 + j) * 16 + mrow]
                    = msg[i][j][r];
    __syncthreads();
    {
        const int ebase = w8 * 24;    // this wave's 24-edge window
        const int d = lane;
        float acc = 0.f;
        int startE = ebase;
        int curn = dst_s[ebase];
#pragma unroll
        for (int e = ebase; e < ebase + 24; e++) {
            acc += xs[e * 68 + d];
            int nxt = (e < ebase + 23) ? dst_s[e + 1] : -1;
            if (nxt != curn) {
                float* dp = agg + (size_t)curn * 64 + d;
                if (startE == ebase || e == ebase + 23) atomicAdd(dp, acc);
                else *dp = acc;
                acc = 0.f; startE = e + 1; curn = nxt;
            }
        }
    }
}

// ---------------- MFMA m+GRU (round-16 proven): bf16x2 GEMMs + register-local gates ----
__global__ __launch_bounds__(256) void k_mgru(float* __restrict__ agg,
                                              const int* __restrict__ offs,
                                              const float* __restrict__ node,
                                              const unsigned short* __restrict__ HHh,
                                              const unsigned short* __restrict__ HHl,
                                              const unsigned short* __restrict__ IHh,
                                              const unsigned short* __restrict__ IHl,
                                              const float* __restrict__ convb,
                                              const float* __restrict__ bih,
                                              const float* __restrict__ bhh,
                                              float* __restrict__ hOut) {
    __shared__ __align__(16) float hs[64][68];   // h, node-major
    __shared__ __align__(16) float ms[64][68];   // m, node-major
    const int tid = threadIdx.x;
    const int lane = tid & 63, wvt = tid >> 6;
    const int quad = lane >> 4, c = lane & 15;
    const int nb = blockIdx.x * 64;
    const f32x4 z4 = {0.f, 0.f, 0.f, 0.f};

    {   // stage h [node][dim]
        int n = tid >> 2, dc = (tid & 3) * 16;
        const float* nr = node + (size_t)(nb + n) * 64 + dc;
#pragma unroll
        for (int j4 = 0; j4 < 4; j4++)
            *(f32x4*)&hs[n][dc + j4 * 4] = *(const f32x4*)(nr + j4 * 4);
    }
    __syncthreads();

    bh8 ah[2], al[2];
#pragma unroll
    for (int kt = 0; kt < 2; kt++) {
#pragma unroll
        for (int j = 0; j < 8; j++) {
            float x = hs[wvt * 16 + c][kt * 32 + quad * 8 + j];
            unsigned short h = f2bfu(x);
            union { unsigned int i; float f; } hv; hv.i = (unsigned int)h << 16;
            unsigned short l = f2bfu(x - hv.f);
            ah[kt][j] = (short)h; al[kt][j] = (short)l;
        }
    }

    f32x4 hacc[16];
#pragma unroll
    for (int ot = 0; ot < 16; ot++) {
        f32x4 a = z4;
#pragma unroll
        for (int kt = 0; kt < 2; kt++) {
            bh8 bh = *(const bh8*)(const void*)(HHh + (ot * 2 + kt) * 512 + lane * 8);
            bh8 bl = *(const bh8*)(const void*)(HHl + (ot * 2 + kt) * 512 + lane * 8);
            a = __builtin_amdgcn_mfma_f32_16x16x32_bf16(ah[kt], bh, a, 0, 0, 0);
            a = __builtin_amdgcn_mfma_f32_16x16x32_bf16(ah[kt], bl, a, 0, 0, 0);
            a = __builtin_amdgcn_mfma_f32_16x16x32_bf16(al[kt], bh, a, 0, 0, 0);
        }
        hacc[ot] = a;
    }

    int nrow[4]; float invd[4];
#pragma unroll
    for (int r = 0; r < 4; r++) {
        nrow[r] = nb + wvt * 16 + quad * 4 + r;
        int dg = offs[nrow[r] + 1] - offs[nrow[r]];
        invd[r] = 1.f / fmaxf((float)dg, 1.f);
    }
#pragma unroll
    for (int k = 0; k < 4; k++) {
        float cb = convb[c + 16 * k];
#pragma unroll
        for (int r = 0; r < 4; r++) {
            size_t ai = (size_t)nrow[r] * 64 + c + 16 * k;
            float m = fmaxf(agg[ai] * invd[r] + cb + hacc[12 + k][r], 0.f);
            agg[ai] = 0.f;
            ms[wvt * 16 + quad * 4 + r][c + 16 * k] = m;
        }
    }
    __syncthreads();

    bh8 amh[2], aml[2];
#pragma unroll
    for (int kt = 0; kt < 2; kt++) {
#pragma unroll
        for (int j = 0; j < 8; j++) {
            float x = ms[wvt * 16 + c][kt * 32 + quad * 8 + j];
            unsigned short h = f2bfu(x);
            union { unsigned int i; float f; } hv; hv.i = (unsigned int)h << 16;
            unsigned short l = f2bfu(x - hv.f);
            amh[kt][j] = (short)h; aml[kt][j] = (short)l;
        }
    }

    f32x4 macc[12];
#pragma unroll
    for (int ot = 0; ot < 12; ot++) {
        f32x4 a = z4;
#pragma unroll
        for (int kt = 0; kt < 2; kt++) {
            bh8 bh = *(const bh8*)(const void*)(IHh + (ot * 2 + kt) * 512 + lane * 8);
            bh8 bl = *(const bh8*)(const void*)(IHl + (ot * 2 + kt) * 512 + lane * 8);
            a = __builtin_amdgcn_mfma_f32_16x16x32_bf16(amh[kt], bh, a, 0, 0, 0);
            a = __builtin_amdgcn_mfma_f32_16x16x32_bf16(amh[kt], bl, a, 0, 0, 0);
            a = __builtin_amdgcn_mfma_f32_16x16x32_bf16(aml[kt], bh, a, 0, 0, 0);
        }
        macc[ot] = a;
    }

#pragma unroll
    for (int k = 0; k < 4; k++) {
        int d = c + 16 * k;
        float bir = bih[d], biz = bih[64 + d], bin = bih[128 + d];
        float bhr = bhh[d], bhz = bhh[64 + d], bhn = bhh[128 + d];
#pragma unroll
        for (int r = 0; r < 4; r++) {
            float rr = sigm(macc[k][r] + bir + hacc[k][r] + bhr);
            float zz = sigm(macc[4 + k][r] + biz + hacc[4 + k][r] + bhz);
            float hnv = hacc[8 + k][r] + bhn;
            float nn = tanhf(macc[8 + k][r] + bin + rr * hnv);
            float hold = hs[wvt * 16 + quad * 4 + r][d];
            hOut[(size_t)nrow[r] * 64 + d] = (1.f - zz) * nn + zz * hold;
        }
    }
}

// ---------------- fused Set2Set x3: state in LDS, two-pass parallel softmax readout ----------
__global__ __launch_bounds__(256) void k_s2s3(const float* __restrict__ node,
                                              const int* __restrict__ gb,
                                              const float* __restrict__ WihT2,
                                              const float* __restrict__ WhhT2,
                                              const float* __restrict__ bih,
                                              const float* __restrict__ bhh,
                                              float* __restrict__ qstar) {
    __shared__ float qvs[128];
    __shared__ float hls[64], cls[64], qsh[64];
    __shared__ float accs[4][64];
    __shared__ float es[256];
    __shared__ float red[4][64];
    __shared__ float sred[4];
    const int b = blockIdx.x, tid = threadIdx.x;
    const int lane = tid & 63, wv = tid >> 6;
    const int start = gb[b], end = gb[b + 1];

    if (tid < 128) qvs[tid] = 0.f;
    else if (tid < 192) hls[tid - 128] = 0.f;
    else cls[tid - 192] = 0.f;
    __syncthreads();

    for (int step = 0; step < 3; step++) {
        float acc = bih[wv * 64 + lane] + bhh[wv * 64 + lane];
        if (step > 0) {
            const float* wih = WihT2 + wv * 64 + lane;
            const float* whh = WhhT2 + wv * 64 + lane;
#pragma unroll 4
            for (int j = 0; j < 128; j++) acc += qvs[j] * wih[(size_t)j * 256];
#pragma unroll 4
            for (int j = 0; j < 64; j++) acc += hls[j] * whh[(size_t)j * 256];
        }
        accs[wv][lane] = acc;
        __syncthreads();
        if (tid < 64) {
            float c = sigm(accs[1][tid]) * cls[tid] + sigm(accs[0][tid]) * tanhf(accs[2][tid]);
            cls[tid] = c;
            float q = sigm(accs[3][tid]) * tanhf(c);
            hls[tid] = q; qsh[tid] = q;
        }
        __syncthreads();
        const float q = qsh[lane];

        float m_run = -1e30f, l_run = 0.f, r_part = 0.f;
        for (int cbase = start; cbase < end; cbase += 256) {
            int cn = min(256, end - cbase);
            for (int i = wv; i < cn; i += 4) {
                float nv = node[(size_t)(cbase + i) * 64 + lane];
                float p = nv * q;
#pragma unroll
                for (int o = 32; o > 0; o >>= 1) p += __shfl_xor(p, o);
                if (lane == 0) es[i] = p;
            }
            __syncthreads();
            float mloc = -1e30f;
            for (int i = tid; i < cn; i += 256) mloc = fmaxf(mloc, es[i]);
#pragma unroll
            for (int o = 32; o > 0; o >>= 1) mloc = fmaxf(mloc, __shfl_xor(mloc, o));
            if (lane == 0) sred[wv] = mloc;
            __syncthreads();
            float m_chunk = fmaxf(fmaxf(sred[0], sred[1]), fmaxf(sred[2], sred[3]));
            float m_new = fmaxf(m_run, m_chunk);
            float sc = expf(m_run - m_new);
            float lloc = 0.f;
            for (int i = tid; i < cn; i += 256) {
                float wgt = expf(es[i] - m_new);
                es[i] = wgt; lloc += wgt;
            }
#pragma unroll
            for (int o = 32; o > 0; o >>= 1) lloc += __shfl_xor(lloc, o);
            __syncthreads();
            if (lane == 0) sred[wv] = lloc;
            __syncthreads();
            float l_chunk = sred[0] + sred[1] + sred[2] + sred[3];
            l_run = l_run * sc + l_chunk;
            r_part *= sc;
            for (int i = wv; i < cn; i += 4)
                r_part += es[i] * node[(size_t)(cbase + i) * 64 + lane];
            m_run = m_new;
            __syncthreads();
        }
        red[wv][lane] = r_part;
        __syncthreads();
        if (tid < 64) {
            float r = red[0][tid] + red[1][tid] + red[2][tid] + red[3][tid];
            qvs[tid] = qsh[tid];
            qvs[64 + tid] = (end > start) ? r / l_run : 0.f;
        }
        __syncthreads();
    }
    if (tid < 128) qstar[(size_t)b * 128 + tid] = qvs[tid];
}

// ---------------- head (coalesced via transposed fc1W) ----------------
__global__ void k_fc(const float* qstar, const float* W1T, const float* b1,
                     const float* W2, const float* b2, float* out) {
    __shared__ float hid[128];
    __shared__ float qs[128];
    int b = blockIdx.x; int t = threadIdx.x;  // 128 threads
    qs[t] = qstar[(size_t)b * 128 + t];
    __syncthreads();
    float acc = b1[t];
    for (int k = 0; k < 128; k++) acc += qs[k] * W1T[k * 128 + t];
    hid[t] = fmaxf(acc, 0.f);
    __syncthreads();
    if (t < 64) {
        float s = hid[t] * W2[t] + hid[t + 64] * W2[t + 64];
        for (int o = 32; o > 0; o >>= 1) s += __shfl_xor(s, o);
        if (t == 0) out[b] = s + b2[0];
    }
}

extern "C" void kernel_launch(void* const* d_in, const int* in_sizes, int n_in,
                              void* d_out, int out_size, void* d_ws, size_t ws_size,
                              hipStream_t stream) {
    const float* x     = (const float*)d_in[0];
    const int*   ei    = (const int*)d_in[1];
    const float* ea    = (const float*)d_in[2];
    const int*   batch = (const int*)d_in[3];
    const float* lin0W = (const float*)d_in[4];
    const float* lin0b = (const float*)d_in[5];
    const float* e1W   = (const float*)d_in[6];
    const float* e1b   = (const float*)d_in[7];
    const float* e2W   = (const float*)d_in[8];
    const float* e2b   = (const float*)d_in[9];
    const float* rootW = (const float*)d_in[10];
    const float* convb = (const float*)d_in[11];
    const float* gWih  = (const float*)d_in[12];
    const float* gWhh  = (const float*)d_in[13];
    const float* gbih  = (const float*)d_in[14];
    const float* gbhh  = (const float*)d_in[15];
    const float* lWih  = (const float*)d_in[16];
    const float* lWhh  = (const float*)d_in[17];
    const float* lbih  = (const float*)d_in[18];
    const float* lbhh  = (const float*)d_in[19];
    const float* fc1W  = (const float*)d_in[20];
    const float* fc1b  = (const float*)d_in[21];
    const float* fc2W  = (const float*)d_in[22];
    const float* fc2b  = (const float*)d_in[23];
    const int* src = ei;
    const int* dst = ei + NE_;

    // workspace carve (~33 MB)
    char* p = (char*)d_ws;
    auto alloc = [&](size_t bytes) -> char* {
        char* r = p; p += (bytes + 255) & ~(size_t)255; return r;
    };
    unsigned short* Bhat3 = (unsigned short*)alloc((size_t)524288 * 2);        // 1.05 MB
    unsigned short* Hhat  = (unsigned short*)alloc((size_t)NE_ * 128 * 2);     // 12.6 MB
    float* nodeA  = (float*)alloc((size_t)NN_ * 64 * 4);
    float* nodeB  = (float*)alloc((size_t)NN_ * 64 * 4);
    float* aggb   = (float*)alloc((size_t)NN_ * 64 * 4);
    int*   deg    = (int*)alloc((size_t)NN_ * 4);
    int*   offs   = (int*)alloc((size_t)(NN_ + 1) * 4);
    int*   head   = (int*)alloc((size_t)NN_ * 4);
    int*   perm   = (int*)alloc((size_t)NE_ * 4);
    int*   bsum   = (int*)alloc((size_t)128 * 4);
    int*   gb     = (int*)alloc((size_t)(NG_ + 1) * 4);
    unsigned short* HHh = (unsigned short*)alloc((size_t)16384 * 2);
    unsigned short* HHl = (unsigned short*)alloc((size_t)16384 * 2);
    unsigned short* IHh = (unsigned short*)alloc((size_t)12288 * 2);
    unsigned short* IHl = (unsigned short*)alloc((size_t)12288 * 2);
    float* WihT2  = (float*)alloc(256 * 128 * 4);
    float* WhhT2  = (float*)alloc(256 * 64 * 4);
    float* fc1WT  = (float*)alloc(128 * 128 * 4);
    float* qstar  = (float*)alloc((size_t)NG_ * 128 * 4);

    k_init<<<(NN_ + NN_ * 64 + 255) / 256, 256, 0, stream>>>(deg, aggb);
    k_lin0<<<NN_ * 64 / 256, 256, 0, stream>>>(x, lin0W, lin0b, nodeA);
    k_cnt<<<NE_ / 256, 256, 0, stream>>>(dst, deg);
    k_scanA<<<NN_ / 256, 256, 0, stream>>>(deg, offs, bsum);
    k_scanC<<<NN_ / 256, 256, 0, stream>>>(bsum, offs, head);
    k_scatter<<<NE_ / 256, 256, 0, stream>>>(dst, head, perm);
    k_gbnd<<<NN_ / 256, 256, 0, stream>>>(batch, gb);
    k_tw<<<256, 256, 0, stream>>>(lWih, lWhh, WihT2, WhhT2, fc1W, fc1WT);
    k_wfrag<<<112, 256, 0, stream>>>(gWih, gWhh, rootW, HHh, HHl, IHh, IHl);
    k_bhat3<<<524288 / 256, 256, 0, stream>>>(e2W, Bhat3);
    k_he<<<NE_ / 16, 256, 0, stream>>>(ea, e1W, e1b, perm, Hhat);   // sorted edge order

    float* curF = nodeA; float* nxtF = nodeB;
    for (int it = 0; it < 3; it++) {
        k_convr<<<NE_ / 192, 512, 0, stream>>>(curF, Hhat, Bhat3, e2b, src, dst, perm, aggb);
        k_mgru<<<NN_ / 64, 256, 0, stream>>>(aggb, offs, curF, HHh, HHl, IHh, IHl,
                                             convb, gbih, gbhh, nxtF);
        float* tf = curF; curF = nxtF; nxtF = tf;
    }

    k_s2s3<<<NG_, 256, 0, stream>>>(curF, gb, WihT2, WhhT2, lbih, lbhh, qstar);
    k_fc<<<NG_, 128, 0, stream>>>(qstar, fc1WT, fc1b, fc2W, fc2b, (float*)d_out);
}

// Round 18
// 426.612 us; speedup vs baseline: 1.0142x; 1.0142x over previous
//
#include <hip/hip_runtime.h>
#include <math.h>

#define NN_ 32768      // nodes
#define NE_ 49152      // edges
#define NG_ 1024       // graphs

typedef short bh8 __attribute__((ext_vector_type(8)));   // 8 bf16 bit-patterns (4 VGPR)
typedef float f32x4 __attribute__((ext_vector_type(4)));

__device__ __forceinline__ unsigned short f2bfu(float f) {   // RNE float->bf16 bits
    union { float f; unsigned int i; } x; x.f = f;
    unsigned int u = x.i;
    u += 0x7FFFu + ((u >> 16) & 1u);
    return (unsigned short)(u >> 16);
}
__device__ __forceinline__ float sigm(float x) { return 1.f / (1.f + expf(-x)); }

// Kept for harness compatibility (unused).
__global__ void MPNN_78632261256134_kernel() {}

// ---------------- fused init zero: deg (int) | agg ----------------
__global__ void k_init(int* deg, float* agg) {
    int i = blockIdx.x * 256 + threadIdx.x;
    if (i < NN_) deg[i] = 0;
    int k = i - NN_;
    if (k >= 0 && k < NN_ * 64) agg[k] = 0.f;
}

// ---------------- lin0 + fused in-degree count ----------------
__global__ void k_lin0(const float* x, const float* W, const float* b, float* node,
                       const int* dst, int* deg) {
    int g = blockIdx.x * 256 + threadIdx.x;   // n*64+d
    int n = g >> 6, d = g & 63;
    const float* xr = x + n * 14;
    const float* wr = W + d * 14;
    float acc = b[d];
    for (int i = 0; i < 14; i++) acc += xr[i] * wr[i];
    node[g] = fmaxf(acc, 0.f);
    if (g < NE_) atomicAdd(&deg[dst[g]], 1);
}

// ---------------- two-phase parallel prefix scan ----------------
__global__ __launch_bounds__(256) void k_scanA(const int* __restrict__ deg,
                                               int* __restrict__ offs,
                                               int* __restrict__ bsum) {
    __shared__ int wtot[4];
    int tid = threadIdx.x, bid = blockIdx.x;
    int i = bid * 256 + tid;
    int v = deg[i];
    int sc = v;
    for (int o = 1; o < 64; o <<= 1) { int u = __shfl_up(sc, o); if ((tid & 63) >= o) sc += u; }
    if ((tid & 63) == 63) wtot[tid >> 6] = sc;
    __syncthreads();
    int wpre = 0;
    for (int k = 0; k < (tid >> 6); k++) wpre += wtot[k];
    offs[i] = sc + wpre - v;              // exclusive within block
    if (tid == 255) bsum[bid] = sc + wpre; // block total
}

// scanC + fused graph segment bounds (same 128x256 grid, independent arrays)
__global__ __launch_bounds__(256) void k_scanC(const int* __restrict__ bsum,
                                               int* __restrict__ offs,
                                               int* __restrict__ head,
                                               const int* __restrict__ batch,
                                               int* __restrict__ gb) {
    __shared__ int boff;
    int tid = threadIdx.x, bid = blockIdx.x;
    if (tid == 0) {
        int s = 0;
        for (int k = 0; k < bid; k++) s += bsum[k];
        boff = s;
    }
    __syncthreads();
    int i = bid * 256 + tid;
    int o = offs[i] + boff;
    offs[i] = o; head[i] = o;
    if (i == NN_ - 1) offs[NN_] = NE_;
    // gbnd
    int n = i;
    int b = batch[n];
    if (n == 0) { for (int g = 0; g <= b; g++) gb[g] = 0; }
    else {
        int pb = batch[n - 1];
        for (int g = pb + 1; g <= b; g++) gb[g] = n;
    }
    if (n == NN_ - 1) { for (int g = b + 1; g <= NG_; g++) gb[g] = NN_; }
}

// ---------------- scatter: perm = edges sorted by dst (counting sort) ----------------
__global__ void k_scatter(const int* __restrict__ dst, int* __restrict__ head,
                          int* __restrict__ perm) {
    int e = blockIdx.x * 256 + threadIdx.x;
    if (e < NE_) { int p = atomicAdd(&head[dst[e]], 1); perm[p] = e; }
}

// ---------------- fused prep: Bhat3 + s2s/fc transposes + GRU bf16x2 weight frags ----------
__global__ void k_prep(const float* __restrict__ e2W, unsigned short* __restrict__ Bhat3,
                       const float* __restrict__ lWih, const float* __restrict__ lWhh,
                       float* __restrict__ WihT2, float* __restrict__ WhhT2,
                       const float* __restrict__ fc1W, float* __restrict__ fc1WT,
                       const float* __restrict__ gWih, const float* __restrict__ gWhh,
                       const float* __restrict__ rootW,
                       unsigned short* __restrict__ HHh, unsigned short* __restrict__ HHl,
                       unsigned short* __restrict__ IHh, unsigned short* __restrict__ IHl) {
    int idx = blockIdx.x * 256 + threadIdx.x;   // < 524288
    {   // Bhat3: frag-contiguous bf16 B [s][w][t][lane][8]
        int j = idx & 7, lane = (idx >> 3) & 63, t = (idx >> 9) & 3,
            w = (idx >> 11) & 3, s = idx >> 13;
        int row = s * 64 + w * 16 + (lane & 15);
        int k = t * 32 + (lane >> 4) * 8 + j;
        Bhat3[idx] = f2bfu(e2W[row * 128 + k]);
    }
    if (idx < 65536) {   // transposes for s2s3 / fc
        int t = idx;
        if (t < 32768) {
            int r = t >> 7, cc = t & 127; WihT2[cc * 256 + r] = lWih[t];
        } else if (t < 49152) {
            int u = t - 32768; int r = u >> 6, cc = u & 63; WhhT2[cc * 256 + r] = lWhh[u];
        } else {
            int u = t - 49152; int r = u >> 7, cc = u & 127; fc1WT[cc * 128 + r] = fc1W[u];
        }
    }
    if (idx < 28672) {   // GRU weight B-fragments, bf16x2 hi/lo
        float w;
        unsigned short *oh, *ol;
        if (idx < 16384) {
            int f = idx;
            int tile = f >> 9, within = f & 511;
            int l = within >> 3, j = within & 7;
            int ot = tile >> 1, kt = tile & 1;
            int col = ot * 16 + (l & 15);
            int k = kt * 32 + (l >> 4) * 8 + j;
            w = (col < 192) ? gWhh[col * 64 + k] : rootW[k * 64 + (col - 192)];
            oh = HHh + f; ol = HHl + f;
        } else {
            int f = idx - 16384;
            int tile = f >> 9, within = f & 511;
            int l = within >> 3, j = within & 7;
            int ot = tile >> 1, kt = tile & 1;
            int col = ot * 16 + (l & 15);
            int k = kt * 32 + (l >> 4) * 8 + j;
            w = gWih[col * 64 + k];
            oh = IHh + f; ol = IHl + f;
        }
        unsigned short hi = f2bfu(w);
        union { unsigned int i; float f; } hv; hv.i = (unsigned int)hi << 16;
        unsigned short lo = f2bfu(w - hv.f);
        *oh = hi; *ol = lo;
    }
}

// ---------------- Hhat: frag-ready He in dst-sorted edge order ----------------
__global__ __launch_bounds__(256) void k_he(const float* __restrict__ ea,
                                            const float* __restrict__ e1W,
                                            const float* __restrict__ e1b,
                                            const int* __restrict__ perm,
                                            unsigned short* __restrict__ Hhat) {
    int tid = threadIdx.x;
    int lane = tid & 63, sub = tid >> 6;
    int gi = blockIdx.x * 4 + sub;            // < 12288
    int etile = gi >> 2, t = gi & 3;
    int e = etile * 16 + (lane & 15), quad = lane >> 4;
    int eo = perm[e];
    const float* ar = ea + (size_t)eo * 4;
    float a0 = ar[0], a1 = ar[1], a2 = ar[2], a3 = ar[3];
    union { unsigned short u[8]; uint4 q; } o;
#pragma unroll
    for (int j = 0; j < 8; j++) {
        int c = t * 32 + quad * 8 + j;
        const float* wr = e1W + c * 4;
        float h = e1b[c] + a0 * wr[0] + a1 * wr[1] + a2 * wr[2] + a3 * wr[3];
        o.u[j] = f2bfu(fmaxf(h, 0.f));
    }
    *(uint4*)(Hhat + (size_t)gi * 512 + lane * 8) = o.q;
}

// ---------------- MFMA NNConv (round-10/16 proven): prefetched body + segment-reduce epilogue ----
#define PS(S) (((S) + soff) & 63)

#define LDB(B, S) {                                                                       \
        const unsigned short* _p = Bhat3 + (size_t)PS(S) * 8192 + w * 2048 + lane * 8;    \
        (B)[0] = *(const bh8*)(const void*)(_p);                                          \
        (B)[1] = *(const bh8*)(const void*)(_p + 512);                                    \
        (B)[2] = *(const bh8*)(const void*)(_p + 1024);                                   \
        (B)[3] = *(const bh8*)(const void*)(_p + 1536); }

#define LDXV(XV, S) {                                                                     \
        int sp_ = PS(S);                                                                  \
        _Pragma("unroll")                                                                 \
        for (int mt_ = 0; mt_ < 4; mt_++)                                                 \
            (XV)[mt_] = *(const f32x4*)(const void*)(xs + sp_ * 68 + mt_ * 16 + quad * 4); }

#define LDBB(BB, S) (BB) = e2b[PS(S) * 64 + w * 16 + mrow];

#define MFMA16(ACC, B) {                                                                  \
        __builtin_amdgcn_s_setprio(1);                                                    \
        _Pragma("unroll")                                                                 \
        for (int t_ = 0; t_ < 4; t_++) {                                                  \
            _Pragma("unroll")                                                             \
            for (int mt_ = 0; mt_ < 4; mt_++)                                             \
                (ACC)[mt_] = __builtin_amdgcn_mfma_f32_16x16x32_bf16(                     \
                    af[mt_][t_], (B)[t_], (t_ == 0) ? z4 : (ACC)[mt_], 0, 0, 0);          \
        }                                                                                 \
        __builtin_amdgcn_s_setprio(0); }

#define CONSUME(ACC, XV, BB) {                                                            \
        _Pragma("unroll")                                                                 \
        for (int mt_ = 0; mt_ < 4; mt_++) {                                               \
            _Pragma("unroll")                                                             \
            for (int r_ = 0; r_ < 4; r_++)                                                \
                msgv[mt_][r_] += (XV)[mt_][r_] * ((ACC)[mt_][r_] + (BB));                 \
        } }

__global__ __launch_bounds__(256, 2) void k_convr(const float* __restrict__ node,
                                                  const unsigned short* __restrict__ Hhat,
                                                  const unsigned short* __restrict__ Bhat3,
                                                  const float* __restrict__ e2b,
                                                  const int* __restrict__ src,
                                                  const int* __restrict__ dst,
                                                  const int* __restrict__ perm,
                                                  float* __restrict__ agg) {
    __shared__ __align__(16) float xs[64 * 68];   // xs[s][e]; reused as msT[e][d] in epilogue
    __shared__ int dst_s[64];

    const int tid = threadIdx.x;
    const int eb = blockIdx.x * 64;
    const int lane = tid & 63, w = tid >> 6;
    const int quad = lane >> 4, mrow = lane & 15;
    const int soff = (blockIdx.x * 37) & 63;

    {
        int r = tid >> 2, c = tid & 3;
        int s = src[perm[eb + r]];
        const float* nr = node + (size_t)s * 64 + c * 16;
#pragma unroll
        for (int j = 0; j < 16; j++) xs[(c * 16 + j) * 68 + r] = nr[j];
        if (tid < 64) dst_s[tid] = dst[perm[eb + tid]];
    }

    bh8 af[4][4];
#pragma unroll
    for (int mt = 0; mt < 4; mt++)
#pragma unroll
        for (int t = 0; t < 4; t++)
            af[mt][t] = *(const bh8*)(const void*)(
                Hhat + (size_t)(((eb >> 4) + mt) * 4 + t) * 512 + lane * 8);
    __syncthreads();

    const f32x4 z4 = {0.f, 0.f, 0.f, 0.f};
    f32x4 msgv[4];
#pragma unroll
    for (int mt = 0; mt < 4; mt++) msgv[mt] = z4;

    bh8 b0[4], b1[4];
    f32x4 xvA[4], xvB[4];
    f32x4 accA[4], accB[4];
    float bbA, bbB;

    // prologue: accA = W(0) issued, b1 = B(1), b0 = B(2), xvA = x(0), bbA = bb(0)
    LDB(b0, 0)
    LDB(b1, 1)
    LDXV(xvA, 0)
    LDBB(bbA, 0)
    MFMA16(accA, b0)
    LDB(b0, 2)

#pragma unroll 1
    for (int s = 0; s < 62; s += 2) {
        MFMA16(accB, b1)          // W(s+1)
        LDB(b1, s + 3)
        LDXV(xvB, s + 1)
        LDBB(bbB, s + 1)
        CONSUME(accA, xvA, bbA)   // consume s
        MFMA16(accA, b0)          // W(s+2)
        LDB(b0, (s + 4) & 63)
        LDXV(xvA, s + 2)
        LDBB(bbA, s + 2)
        CONSUME(accB, xvB, bbB)   // consume s+1
    }
    MFMA16(accB, b1)              // W(63)
    CONSUME(accA, xvA, bbA)       // s = 62
    LDXV(xvB, 63)
    LDBB(bbB, 63)
    CONSUME(accB, xvB, bbB)       // s = 63

    // ---- epilogue: transpose msgv via xs, per-window segment reduce ----
    __syncthreads();   // all waves done reading xs
#pragma unroll
    for (int mt = 0; mt < 4; mt++)
#pragma unroll
        for (int r = 0; r < 4; r++)
            xs[(mt * 16 + quad * 4 + r) * 68 + w * 16 + mrow] = msgv[mt][r];
    __syncthreads();
    {
        const int ebase = w * 16;     // this wave's 16-edge window
        const int d = lane;
        float acc = 0.f;
        int startE = ebase;
        int curn = dst_s[ebase];
#pragma unroll
        for (int e = ebase; e < ebase + 16; e++) {
            acc += xs[e * 68 + d];
            int nxt = (e < ebase + 15) ? dst_s[e + 1] : -1;
            if (nxt != curn) {
                float* dp = agg + (size_t)curn * 64 + d;
                if (startE == ebase || e == ebase + 15) atomicAdd(dp, acc);
                else *dp = acc;
                acc = 0.f; startE = e + 1; curn = nxt;
            }
        }
    }
}

// ---------------- MFMA m+GRU (round-16 proven): bf16x2 GEMMs + register-local gates ----
__global__ __launch_bounds__(256) void k_mgru(float* __restrict__ agg,
                                              const int* __restrict__ offs,
                                              const float* __restrict__ node,
                                              const unsigned short* __restrict__ HHh,
                                              const unsigned short* __restrict__ HHl,
                                              const unsigned short* __restrict__ IHh,
                                              const unsigned short* __restrict__ IHl,
                                              const float* __restrict__ convb,
                                              const float* __restrict__ bih,
                                              const float* __restrict__ bhh,
                                              float* __restrict__ hOut) {
    __shared__ __align__(16) float hs[64][68];   // h, node-major
    __shared__ __align__(16) float ms[64][68];   // m, node-major
    const int tid = threadIdx.x;
    const int lane = tid & 63, wvt = tid >> 6;
    const int quad = lane >> 4, c = lane & 15;
    const int nb = blockIdx.x * 64;
    const f32x4 z4 = {0.f, 0.f, 0.f, 0.f};

    {   // stage h [node][dim]
        int n = tid >> 2, dc = (tid & 3) * 16;
        const float* nr = node + (size_t)(nb + n) * 64 + dc;
#pragma unroll
        for (int j4 = 0; j4 < 4; j4++)
            *(f32x4*)&hs[n][dc + j4 * 4] = *(const f32x4*)(nr + j4 * 4);
    }
    __syncthreads();

    bh8 ah[2], al[2];
#pragma unroll
    for (int kt = 0; kt < 2; kt++) {
#pragma unroll
        for (int j = 0; j < 8; j++) {
            float x = hs[wvt * 16 + c][kt * 32 + quad * 8 + j];
            unsigned short h = f2bfu(x);
            union { unsigned int i; float f; } hv; hv.i = (unsigned int)h << 16;
            unsigned short l = f2bfu(x - hv.f);
            ah[kt][j] = (short)h; al[kt][j] = (short)l;
        }
    }

    f32x4 hacc[16];
#pragma unroll
    for (int ot = 0; ot < 16; ot++) {
        f32x4 a = z4;
#pragma unroll
        for (int kt = 0; kt < 2; kt++) {
            bh8 bh = *(const bh8*)(const void*)(HHh + (ot * 2 + kt) * 512 + lane * 8);
            bh8 bl = *(const bh8*)(const void*)(HHl + (ot * 2 + kt) * 512 + lane * 8);
            a = __builtin_amdgcn_mfma_f32_16x16x32_bf16(ah[kt], bh, a, 0, 0, 0);
            a = __builtin_amdgcn_mfma_f32_16x16x32_bf16(ah[kt], bl, a, 0, 0, 0);
            a = __builtin_amdgcn_mfma_f32_16x16x32_bf16(al[kt], bh, a, 0, 0, 0);
        }
        hacc[ot] = a;
    }

    int nrow[4]; float invd[4];
#pragma unroll
    for (int r = 0; r < 4; r++) {
        nrow[r] = nb + wvt * 16 + quad * 4 + r;
        int dg = offs[nrow[r] + 1] - offs[nrow[r]];
        invd[r] = 1.f / fmaxf((float)dg, 1.f);
    }
#pragma unroll
    for (int k = 0; k < 4; k++) {
        float cb = convb[c + 16 * k];
#pragma unroll
        for (int r = 0; r < 4; r++) {
            size_t ai = (size_t)nrow[r] * 64 + c + 16 * k;
            float m = fmaxf(agg[ai] * invd[r] + cb + hacc[12 + k][r], 0.f);
            agg[ai] = 0.f;
            ms[wvt * 16 + quad * 4 + r][c + 16 * k] = m;
        }
    }
    __syncthreads();

    bh8 amh[2], aml[2];
#pragma unroll
    for (int kt = 0; kt < 2; kt++) {
#pragma unroll
        for (int j = 0; j < 8; j++) {
            float x = ms[wvt * 16 + c][kt * 32 + quad * 8 + j];
            unsigned short h = f2bfu(x);
            union { unsigned int i; float f; } hv; hv.i = (unsigned int)h << 16;
            unsigned short l = f2bfu(x - hv.f);
            amh[kt][j] = (short)h; aml[kt][j] = (short)l;
        }
    }

    f32x4 macc[12];
#pragma unroll
    for (int ot = 0; ot < 12; ot++) {
        f32x4 a = z4;
#pragma unroll
        for (int kt = 0; kt < 2; kt++) {
            bh8 bh = *(const bh8*)(const void*)(IHh + (ot * 2 + kt) * 512 + lane * 8);
            bh8 bl = *(const bh8*)(const void*)(IHl + (ot * 2 + kt) * 512 + lane * 8);
            a = __builtin_amdgcn_mfma_f32_16x16x32_bf16(amh[kt], bh, a, 0, 0, 0);
            a = __builtin_amdgcn_mfma_f32_16x16x32_bf16(amh[kt], bl, a, 0, 0, 0);
            a = __builtin_amdgcn_mfma_f32_16x16x32_bf16(aml[kt], bh, a, 0, 0, 0);
        }
        macc[ot] = a;
    }

#pragma unroll
    for (int k = 0; k < 4; k++) {
        int d = c + 16 * k;
        float bir = bih[d], biz = bih[64 + d], bin = bih[128 + d];
        float bhr = bhh[d], bhz = bhh[64 + d], bhn = bhh[128 + d];
#pragma unroll
        for (int r = 0; r < 4; r++) {
            float rr = sigm(macc[k][r] + bir + hacc[k][r] + bhr);
            float zz = sigm(macc[4 + k][r] + biz + hacc[4 + k][r] + bhz);
            float hnv = hacc[8 + k][r] + bhn;
            float nn = tanhf(macc[8 + k][r] + bin + rr * hnv);
            float hold = hs[wvt * 16 + quad * 4 + r][d];
            hOut[(size_t)nrow[r] * 64 + d] = (1.f - zz) * nn + zz * hold;
        }
    }
}

// ---------------- fused Set2Set x3: state in LDS, two-pass parallel softmax readout ----------
__global__ __launch_bounds__(256) void k_s2s3(const float* __restrict__ node,
                                              const int* __restrict__ gb,
                                              const float* __restrict__ WihT2,
                                              const float* __restrict__ WhhT2,
                                              const float* __restrict__ bih,
                                              const float* __restrict__ bhh,
                                              float* __restrict__ qstar) {
    __shared__ float qvs[128];
    __shared__ float hls[64], cls[64], qsh[64];
    __shared__ float accs[4][64];
    __shared__ float es[256];
    __shared__ float red[4][64];
    __shared__ float sred[4];
    const int b = blockIdx.x, tid = threadIdx.x;
    const int lane = tid & 63, wv = tid >> 6;
    const int start = gb[b], end = gb[b + 1];

    if (tid < 128) qvs[tid] = 0.f;
    else if (tid < 192) hls[tid - 128] = 0.f;
    else cls[tid - 192] = 0.f;
    __syncthreads();

    for (int step = 0; step < 3; step++) {
        float acc = bih[wv * 64 + lane] + bhh[wv * 64 + lane];
        if (step > 0) {
            const float* wih = WihT2 + wv * 64 + lane;
            const float* whh = WhhT2 + wv * 64 + lane;
#pragma unroll 4
            for (int j = 0; j < 128; j++) acc += qvs[j] * wih[(size_t)j * 256];
#pragma unroll 4
            for (int j = 0; j < 64; j++) acc += hls[j] * whh[(size_t)j * 256];
        }
        accs[wv][lane] = acc;
        __syncthreads();
        if (tid < 64) {
            float c = sigm(accs[1][tid]) * cls[tid] + sigm(accs[0][tid]) * tanhf(accs[2][tid]);
            cls[tid] = c;
            float q = sigm(accs[3][tid]) * tanhf(c);
            hls[tid] = q; qsh[tid] = q;
        }
        __syncthreads();
        const float q = qsh[lane];

        float m_run = -1e30f, l_run = 0.f, r_part = 0.f;
        for (int cbase = start; cbase < end; cbase += 256) {
            int cn = min(256, end - cbase);
            for (int i = wv; i < cn; i += 4) {
                float nv = node[(size_t)(cbase + i) * 64 + lane];
                float p = nv * q;
#pragma unroll
                for (int o = 32; o > 0; o >>= 1) p += __shfl_xor(p, o);
                if (lane == 0) es[i] = p;
            }
            __syncthreads();
            float mloc = -1e30f;
            for (int i = tid; i < cn; i += 256) mloc = fmaxf(mloc, es[i]);
#pragma unroll
            for (int o = 32; o > 0; o >>= 1) mloc = fmaxf(mloc, __shfl_xor(mloc, o));
            if (lane == 0) sred[wv] = mloc;
            __syncthreads();
            float m_chunk = fmaxf(fmaxf(sred[0], sred[1]), fmaxf(sred[2], sred[3]));
            float m_new = fmaxf(m_run, m_chunk);
            float sc = expf(m_run - m_new);
            float lloc = 0.f;
            for (int i = tid; i < cn; i += 256) {
                float wgt = expf(es[i] - m_new);
                es[i] = wgt; lloc += wgt;
            }
#pragma unroll
            for (int o = 32; o > 0; o >>= 1) lloc += __shfl_xor(lloc, o);
            __syncthreads();
            if (lane == 0) sred[wv] = lloc;
            __syncthreads();
            float l_chunk = sred[0] + sred[1] + sred[2] + sred[3];
            l_run = l_run * sc + l_chunk;
            r_part *= sc;
            for (int i = wv; i < cn; i += 4)
                r_part += es[i] * node[(size_t)(cbase + i) * 64 + lane];
            m_run = m_new;
            __syncthreads();
        }
        red[wv][lane] = r_part;
        __syncthreads();
        if (tid < 64) {
            float r = red[0][tid] + red[1][tid] + red[2][tid] + red[3][tid];
            qvs[tid] = qsh[tid];
            qvs[64 + tid] = (end > start) ? r / l_run : 0.f;
        }
        __syncthreads();
    }
    if (tid < 128) qstar[(size_t)b * 128 + tid] = qvs[tid];
}

// ---------------- head (coalesced via transposed fc1W) ----------------
__global__ void k_fc(const float* qstar, const float* W1T, const float* b1,
                     const float* W2, const float* b2, float* out) {
    __shared__ float hid[128];
    __shared__ float qs[128];
    int b = blockIdx.x; int t = threadIdx.x;  // 128 threads
    qs[t] = qstar[(size_t)b * 128 + t];
    __syncthreads();
    float acc = b1[t];
    for (int k = 0; k < 128; k++) acc += qs[k] * W1T[k * 128 + t];
    hid[t] = fmaxf(acc, 0.f);
    __syncthreads();
    if (t < 64) {
        float s = hid[t] * W2[t] + hid[t + 64] * W2[t + 64];
        for (int o = 32; o > 0; o >>= 1) s += __shfl_xor(s, o);
        if (t == 0) out[b] = s + b2[0];
    }
}

extern "C" void kernel_launch(void* const* d_in, const int* in_sizes, int n_in,
                              void* d_out, int out_size, void* d_ws, size_t ws_size,
                              hipStream_t stream) {
    const float* x     = (const float*)d_in[0];
    const int*   ei    = (const int*)d_in[1];
    const float* ea    = (const float*)d_in[2];
    const int*   batch = (const int*)d_in[3];
    const float* lin0W = (const float*)d_in[4];
    const float* lin0b = (const float*)d_in[5];
    const float* e1W   = (const float*)d_in[6];
    const float* e1b   = (const float*)d_in[7];
    const float* e2W   = (const float*)d_in[8];
    const float* e2b   = (const float*)d_in[9];
    const float* rootW = (const float*)d_in[10];
    const float* convb = (const float*)d_in[11];
    const float* gWih  = (const float*)d_in[12];
    const float* gWhh  = (const float*)d_in[13];
    const float* gbih  = (const float*)d_in[14];
    const float* gbhh  = (const float*)d_in[15];
    const float* lWih  = (const float*)d_in[16];
    const float* lWhh  = (const float*)d_in[17];
    const float* lbih  = (const float*)d_in[18];
    const float* lbhh  = (const float*)d_in[19];
    const float* fc1W  = (const float*)d_in[20];
    const float* fc1b  = (const float*)d_in[21];
    const float* fc2W  = (const float*)d_in[22];
    const float* fc2b  = (const float*)d_in[23];
    const int* src = ei;
    const int* dst = ei + NE_;

    // workspace carve (~33 MB)
    char* p = (char*)d_ws;
    auto alloc = [&](size_t bytes) -> char* {
        char* r = p; p += (bytes + 255) & ~(size_t)255; return r;
    };
    unsigned short* Bhat3 = (unsigned short*)alloc((size_t)524288 * 2);        // 1.05 MB
    unsigned short* Hhat  = (unsigned short*)alloc((size_t)NE_ * 128 * 2);     // 12.6 MB
    float* nodeA  = (float*)alloc((size_t)NN_ * 64 * 4);
    float* nodeB  = (float*)alloc((size_t)NN_ * 64 * 4);
    float* aggb   = (float*)alloc((size_t)NN_ * 64 * 4);
    int*   deg    = (int*)alloc((size_t)NN_ * 4);
    int*   offs   = (int*)alloc((size_t)(NN_ + 1) * 4);
    int*   head   = (int*)alloc((size_t)NN_ * 4);
    int*   perm   = (int*)alloc((size_t)NE_ * 4);
    int*   bsum   = (int*)alloc((size_t)128 * 4);
    int*   gb     = (int*)alloc((size_t)(NG_ + 1) * 4);
    unsigned short* HHh = (unsigned short*)alloc((size_t)16384 * 2);
    unsigned short* HHl = (unsigned short*)alloc((size_t)16384 * 2);
    unsigned short* IHh = (unsigned short*)alloc((size_t)12288 * 2);
    unsigned short* IHl = (unsigned short*)alloc((size_t)12288 * 2);
    float* WihT2  = (float*)alloc(256 * 128 * 4);
    float* WhhT2  = (float*)alloc(256 * 64 * 4);
    float* fc1WT  = (float*)alloc(128 * 128 * 4);
    float* qstar  = (float*)alloc((size_t)NG_ * 128 * 4);

    k_init<<<(NN_ + NN_ * 64 + 255) / 256, 256, 0, stream>>>(deg, aggb);
    k_lin0<<<NN_ * 64 / 256, 256, 0, stream>>>(x, lin0W, lin0b, nodeA, dst, deg);
    k_scanA<<<NN_ / 256, 256, 0, stream>>>(deg, offs, bsum);
    k_scanC<<<NN_ / 256, 256, 0, stream>>>(bsum, offs, head, batch, gb);
    k_scatter<<<NE_ / 256, 256, 0, stream>>>(dst, head, perm);
    k_prep<<<524288 / 256, 256, 0, stream>>>(e2W, Bhat3, lWih, lWhh, WihT2, WhhT2,
                                             fc1W, fc1WT, gWih, gWhh, rootW,
                                             HHh, HHl, IHh, IHl);
    k_he<<<NE_ / 16, 256, 0, stream>>>(ea, e1W, e1b, perm, Hhat);   // sorted edge order

    float* curF = nodeA; float* nxtF = nodeB;
    for (int it = 0; it < 3; it++) {
        k_convr<<<NE_ / 64, 256, 0, stream>>>(curF, Hhat, Bhat3, e2b, src, dst, perm, aggb);
        k_mgru<<<NN_ / 64, 256, 0, stream>>>(aggb, offs, curF, HHh, HHl, IHh, IHl,
                                             convb, gbih, gbhh, nxtF);
        float* tf = curF; curF = nxtF; nxtF = tf;
    }

    k_s2s3<<<NG_, 256, 0, stream>>>(curF, gb, WihT2, WhhT2, lbih, lbhh, qstar);
    k_fc<<<NG_, 128, 0, stream>>>(qstar, fc1WT, fc1b, fc2W, fc2b, (float*)d_out);
}